// Round 1
// baseline (194.978 us; speedup 1.0000x reference)
//
#include <hip/hip_runtime.h>
#include <math.h>

#define BB 2
#define HH 32
#define WWD 32
#define CCH 64
#define KLEN 15
#define KK2 225
#define NG 4
#define NGC 16
#define NPIX (BB*HH*WWD)      // 2048
#define OFFC (NG*KK2*2)       // 1800
#define MSKC (NG*KK2)         // 900

// ws layout (float offsets)
#define WS_KW    0                       // 14400 (kernel MLP out, [225][64] row-major)
#define WS_ENV   14400                   // 225
#define WS_XPROJ 16384                   // 131072
#define WS_XDW   (16384+131072)          // 131072
#define WS_OUT   (16384+2*131072)        // 131072
#define WS_POOL  (16384+3*131072)        // 128
#define WS_GATE  (WS_POOL+128)           // 128
#define WS_ENTP  (WS_GATE+128)           // 2048
#define WS_OFFP  (WS_ENTP+2048)          // 2048

__global__ __launch_bounds__(256) void k_setup(
    const float* __restrict__ raw_sigma,
    const float* __restrict__ w_k1, const float* __restrict__ b_k1,
    const float* __restrict__ w_k2, const float* __restrict__ b_k2,
    const float* __restrict__ w_k3, const float* __restrict__ b_k3,
    float* __restrict__ ws)
{
  __shared__ float s_red[256];
  __shared__ float s_sum;
  int t = threadIdx.x;
  float sp = log1pf(expf(raw_sigma[0]));
  float sigma = fminf(fmaxf(sp, 1e-3f), 0.5f);
  float envv = 0.f, gi = 0.f, gj = 0.f;
  if (t < KK2) {
    int i = t / 15, j = t % 15;
    gi = -0.5f + (float)i * (1.0f/14.0f);
    gj = -0.5f + (float)j * (1.0f/14.0f);
    envv = expf(-(gi*gi + gj*gj) / (2.f*sigma*sigma));
  }
  s_red[t] = envv;
  __syncthreads();
  for (int s = 128; s > 0; s >>= 1) { if (t < s) s_red[t] += s_red[t+s]; __syncthreads(); }
  if (t == 0) s_sum = fmaxf(s_red[0], 1e-8f);
  __syncthreads();
  if (t < KK2) {
    ws[WS_ENV + t] = envv / s_sum;
    // kernel MLP: pos = (gi*2, gj*2) -> 32 -> 32 -> 64
    float p0 = gi * 2.f, p1 = gj * 2.f;
    float h1[32], h2[32];
    #pragma unroll
    for (int r = 0; r < 32; r++) {
      float a = p0 * w_k1[r] + p1 * w_k1[32 + r] + b_k1[r];
      h1[r] = a / (1.f + expf(-a));
    }
    #pragma unroll
    for (int r = 0; r < 32; r++) {
      float a = b_k2[r];
      #pragma unroll
      for (int q = 0; q < 32; q++) a += h1[q] * w_k2[q*32 + r];
      h2[r] = a / (1.f + expf(-a));
    }
    for (int j2 = 0; j2 < 64; j2++) {
      float a = b_k3[j2];
      #pragma unroll
      for (int q = 0; q < 32; q++) a += h2[q] * w_k3[q*64 + j2];
      ws[WS_KW + t*64 + j2] = a;   // kw[g][p][c] = ws[WS_KW + g*3600 + p*16 + c]
    }
  }
}

__global__ __launch_bounds__(64) void k_proj(
    const float* __restrict__ x,
    const float* __restrict__ w_ip, const float* __restrict__ b_ip,
    const float* __restrict__ w_dw, const float* __restrict__ b_dw,
    const float* __restrict__ w_pw, const float* __restrict__ b_pw,
    float* __restrict__ ws)
{
  int pix = blockIdx.x;
  int b = pix >> 10, h = (pix >> 5) & 31, w = pix & 31;
  int c = threadIdx.x;
  __shared__ float xs[64], ys[64];
  xs[c] = x[pix*64 + c];
  float acc = b_dw[c];
  #pragma unroll
  for (int dh = -1; dh <= 1; dh++) {
    int hh = h + dh;
    if (hh < 0 || hh > 31) continue;
    #pragma unroll
    for (int dw2 = -1; dw2 <= 1; dw2++) {
      int wp = w + dw2;
      if (wp < 0 || wp > 31) continue;
      acc += x[(((b*32 + hh)*32 + wp) << 6) + c] * w_dw[((dh+1)*3 + (dw2+1))*64 + c];
    }
  }
  ys[c] = acc / (1.f + expf(-acc));   // SiLU
  __syncthreads();
  float p1 = b_ip[c], p2 = b_pw[c];
  #pragma unroll 8
  for (int k = 0; k < 64; k++) {
    p1 += xs[k] * w_ip[k*64 + c];
    p2 += ys[k] * w_pw[k*64 + c];
  }
  ws[WS_XPROJ + pix*64 + c] = p1;
  ws[WS_XDW   + pix*64 + c] = p2;
}

__global__ __launch_bounds__(256) void k_main(
    const float* __restrict__ base_scale,
    const float* __restrict__ w_off, const float* __restrict__ b_off,
    const float* __restrict__ w_msk, const float* __restrict__ b_msk,
    float* __restrict__ ws)
{
  __shared__ float xd[64];
  __shared__ float off_s[OFFC];
  __shared__ float msk_s[MSKC];
  __shared__ float red[256];
  __shared__ float ent_sh[4];
  int t = threadIdx.x;
  int pix = blockIdx.x;
  int b = pix >> 10, h = (pix >> 5) & 31, w = pix & 31;
  if (t < 64) xd[t] = ws[WS_XDW + pix*64 + t];
  __syncthreads();
  float scale = base_scale[0];
  float offreg = 0.f;
  for (int o = t; o < OFFC; o += 256) {
    float a = b_off[o];
    const float* wp = w_off + o;
    #pragma unroll 16
    for (int k = 0; k < 64; k++) a += xd[k] * wp[k*OFFC];
    a *= scale;
    off_s[o] = a;
    offreg += a * a;
  }
  for (int o = t; o < MSKC; o += 256) {
    float a = b_msk[o];
    const float* wp = w_msk + o;
    #pragma unroll 16
    for (int k = 0; k < 64; k++) a += xd[k] * wp[k*MSKC];
    msk_s[o] = a;
  }
  red[t] = offreg;
  __syncthreads();
  for (int s = 128; s > 0; s >>= 1) { if (t < s) red[t] += red[t+s]; __syncthreads(); }
  if (t == 0) ws[WS_OFFP + pix] = red[0];

  // per-group softmax: wave g handles group g (225 elems, lane covers p=lane+64k)
  int g = t >> 6, lane = t & 63;
  float v[4];
  float m = -INFINITY;
  #pragma unroll
  for (int kk = 0; kk < 4; kk++) {
    int p = lane + kk*64;
    if (p < KK2) { v[kk] = msk_s[g*KK2 + p] * ws[WS_ENV + p]; m = fmaxf(m, v[kk]); }
    else v[kk] = -INFINITY;
  }
  #pragma unroll
  for (int s = 32; s > 0; s >>= 1) m = fmaxf(m, __shfl_xor(m, s));
  float sum = 0.f;
  #pragma unroll
  for (int kk = 0; kk < 4; kk++) {
    int p = lane + kk*64;
    if (p < KK2) { v[kk] = expf(v[kk] - m); sum += v[kk]; }
  }
  #pragma unroll
  for (int s = 32; s > 0; s >>= 1) sum += __shfl_xor(sum, s);
  float inv = 1.f / sum;
  float ent = 0.f;
  #pragma unroll
  for (int kk = 0; kk < 4; kk++) {
    int p = lane + kk*64;
    if (p < KK2) {
      float a = v[kk] * inv;
      msk_s[g*KK2 + p] = a;               // attn overwrites raw mask
      ent += a * logf(a + 1e-8f);
    }
  }
  #pragma unroll
  for (int s = 32; s > 0; s >>= 1) ent += __shfl_xor(ent, s);
  if (lane == 0) ent_sh[g] = ent;
  __syncthreads();
  if (t == 0) ws[WS_ENTP + pix] = ent_sh[0] + ent_sh[1] + ent_sh[2] + ent_sh[3];

  // sampling: lane = str*16 + cc; cc = channel within group, str = tap stream
  int cc = lane & 15, str = lane >> 4;
  const float* xp = ws + WS_XPROJ + ((b * 1024) << 6);
  const float* kwf = ws + WS_KW + g*3600 + cc;
  int cbase = g*16 + cc;
  float acc = 0.f;
  for (int p = str; p < KK2; p += 4) {
    float at = msk_s[g*KK2 + p];
    float o0 = off_s[g*450 + p*2 + 0];
    float o1 = off_s[g*450 + p*2 + 1];
    float abs_h = (float)h + (float)(p/15 - 7) + o0;
    float abs_w = (float)w + (float)(p%15 - 7) + o1;
    float ah = fminf(fmaxf(abs_h, 0.f), 31.f);
    float aw = fminf(fmaxf(abs_w, 0.f), 31.f);
    int hf = (int)floorf(ah);
    int wf = (int)floorf(aw);
    int hc = min(hf + 1, 31), wc = min(wf + 1, 31);
    float hw_ = ah - (float)hf, ww_ = aw - (float)wf;
    float valid = (abs_h < 0.f || abs_h > 31.f || abs_w < 0.f || abs_w > 31.f) ? 0.f : 1.f;
    float vff = xp[((hf*32 + wf) << 6) + cbase];
    float vfc = xp[((hf*32 + wc) << 6) + cbase];
    float vcf = xp[((hc*32 + wf) << 6) + cbase];
    float vcc = xp[((hc*32 + wc) << 6) + cbase];
    float bil = (1.f-hw_)*((1.f-ww_)*vff + ww_*vfc) + hw_*((1.f-ww_)*vcf + ww_*vcc);
    acc += bil * valid * kwf[p*16] * at;
  }
  acc += __shfl_xor(acc, 16);
  acc += __shfl_xor(acc, 32);
  if (lane < 16) ws[WS_OUT + pix*64 + g*16 + lane] = acc;
}

__global__ __launch_bounds__(256) void k_reduce(float* __restrict__ ws, float* __restrict__ d_out)
{
  __shared__ float red[256];
  int t = threadIdx.x, blk = blockIdx.x;
  if (blk < 2) {
    int b = blk;
    int c = t & 63, str = t >> 6;
    float s = 0.f;
    for (int p = str; p < 1024; p += 4) s += ws[WS_OUT + ((b*1024 + p) << 6) + c];
    red[t] = s;
    __syncthreads();
    if (t < 64) ws[WS_POOL + b*64 + t] =
      (red[t] + red[t+64] + red[t+128] + red[t+192]) * (1.f/1024.f);
  } else if (blk == 2) {
    float s = 0.f;
    for (int i = t; i < NPIX; i += 256) s += ws[WS_ENTP + i];
    red[t] = s; __syncthreads();
    for (int sf = 128; sf > 0; sf >>= 1) { if (t < sf) red[t] += red[t+sf]; __syncthreads(); }
    if (t == 0) d_out[NPIX*64 + 1] = red[0] * (1.f/8192.f);     // -entropy
  } else {
    float s = 0.f;
    for (int i = t; i < NPIX; i += 256) s += ws[WS_OFFP + i];
    red[t] = s; __syncthreads();
    for (int sf = 128; sf > 0; sf >>= 1) { if (t < sf) red[t] += red[t+sf]; __syncthreads(); }
    if (t == 0) d_out[NPIX*64] = red[0] * (1.f/3686400.f);      // offset_reg
  }
}

__global__ __launch_bounds__(128) void k_se(
    const float* __restrict__ w_fc1, const float* __restrict__ b_fc1,
    const float* __restrict__ w_fc2, const float* __restrict__ b_fc2,
    float* __restrict__ ws)
{
  __shared__ float hsh[2][16];
  int t = threadIdx.x;
  if (t < 32) {
    int b = t >> 4, r = t & 15;
    float a = b_fc1[r];
    for (int c = 0; c < 64; c++) a += ws[WS_POOL + b*64 + c] * w_fc1[c*16 + r];
    hsh[b][r] = a / (1.f + expf(-a));
  }
  __syncthreads();
  int b = t >> 6, c = t & 63;
  float a = b_fc2[c];
  #pragma unroll
  for (int r = 0; r < 16; r++) a += hsh[b][r] * w_fc2[r*64 + c];
  ws[WS_GATE + b*64 + c] = 1.f / (1.f + expf(-a));
}

__global__ __launch_bounds__(64) void k_final(
    const float* __restrict__ w_op, const float* __restrict__ b_op,
    const float* __restrict__ ws, float* __restrict__ d_out)
{
  int pix = blockIdx.x, b = pix >> 10, c = threadIdx.x;
  __shared__ float sc[64];
  sc[c] = ws[WS_OUT + pix*64 + c] * ws[WS_GATE + b*64 + c];
  __syncthreads();
  float a = b_op[c];
  #pragma unroll 8
  for (int k = 0; k < 64; k++) a += sc[k] * w_op[k*64 + c];
  d_out[pix*64 + c] = a;
}

extern "C" void kernel_launch(void* const* d_in, const int* in_sizes, int n_in,
                              void* d_out, int out_size, void* d_ws, size_t ws_size,
                              hipStream_t stream)
{
  const float* x     = (const float*)d_in[0];
  const float* rsig  = (const float*)d_in[1];
  const float* bos   = (const float*)d_in[2];
  const float* w_ip  = (const float*)d_in[3];
  const float* b_ip  = (const float*)d_in[4];
  const float* w_op  = (const float*)d_in[5];
  const float* b_op  = (const float*)d_in[6];
  const float* w_dw  = (const float*)d_in[7];
  const float* b_dw  = (const float*)d_in[8];
  const float* w_pw  = (const float*)d_in[9];
  const float* b_pw  = (const float*)d_in[10];
  const float* w_off = (const float*)d_in[11];
  const float* b_off = (const float*)d_in[12];
  const float* w_msk = (const float*)d_in[13];
  const float* b_msk = (const float*)d_in[14];
  const float* w_k1  = (const float*)d_in[15];
  const float* b_k1  = (const float*)d_in[16];
  const float* w_k2  = (const float*)d_in[17];
  const float* b_k2  = (const float*)d_in[18];
  const float* w_k3  = (const float*)d_in[19];
  const float* b_k3  = (const float*)d_in[20];
  const float* w_fc1 = (const float*)d_in[21];
  const float* b_fc1 = (const float*)d_in[22];
  const float* w_fc2 = (const float*)d_in[23];
  const float* b_fc2 = (const float*)d_in[24];
  float* ws  = (float*)d_ws;
  float* out = (float*)d_out;

  hipLaunchKernelGGL(k_setup, dim3(1), dim3(256), 0, stream,
                     rsig, w_k1, b_k1, w_k2, b_k2, w_k3, b_k3, ws);
  hipLaunchKernelGGL(k_proj, dim3(NPIX), dim3(64), 0, stream,
                     x, w_ip, b_ip, w_dw, b_dw, w_pw, b_pw, ws);
  hipLaunchKernelGGL(k_main, dim3(NPIX), dim3(256), 0, stream,
                     bos, w_off, b_off, w_msk, b_msk, ws);
  hipLaunchKernelGGL(k_reduce, dim3(4), dim3(256), 0, stream, ws, out);
  hipLaunchKernelGGL(k_se, dim3(1), dim3(128), 0, stream,
                     w_fc1, b_fc1, w_fc2, b_fc2, ws);
  hipLaunchKernelGGL(k_final, dim3(NPIX), dim3(64), 0, stream,
                     w_op, b_op, ws, out);
}

// Round 2
// 117.076 us; speedup vs baseline: 1.6654x; 1.6654x over previous
//
#include <hip/hip_runtime.h>
#include <math.h>

#define KK2 225
#define NPIX 2048
#define OFFC 1800
#define MSKC 900

// ws layout (float offsets)
#define WS_KW    0                       // 14400 (kernel MLP out, [225][64] row-major)
#define WS_ENV   14400                   // 225 (unused now, env computed in k_main)
#define WS_XPROJ 16384                   // 131072
#define WS_XDW   (16384+131072)          // 131072
#define WS_OUT   (16384+2*131072)        // 131072
#define WS_POOL  (16384+3*131072)        // 128
#define WS_GATE  (WS_POOL+128)           // 128
#define WS_ENTP  (WS_GATE+128)           // 2048
#define WS_OFFP  (WS_ENTP+2048)          // 512

__device__ __forceinline__ float silu(float a) { return a / (1.f + __expf(-a)); }

// ---- kernel MLP: one block (64 threads) per tap ----
__global__ __launch_bounds__(64) void k_kmlp(
    const float* __restrict__ w_k1, const float* __restrict__ b_k1,
    const float* __restrict__ w_k2, const float* __restrict__ b_k2,
    const float* __restrict__ w_k3, const float* __restrict__ b_k3,
    float* __restrict__ ws)
{
  __shared__ float h1s[32], h2s[32];
  int tap = blockIdx.x;          // 0..224
  int lane = threadIdx.x;        // 0..63
  int i = tap / 15, j = tap % 15;
  float gi = -0.5f + (float)i * (1.0f/14.0f);
  float gj = -0.5f + (float)j * (1.0f/14.0f);
  float p0 = gi * 2.f, p1 = gj * 2.f;
  if (lane < 32) {
    float a = p0 * w_k1[lane] + p1 * w_k1[32 + lane] + b_k1[lane];
    h1s[lane] = silu(a);
  }
  __syncthreads();
  if (lane < 32) {
    float a = b_k2[lane];
    #pragma unroll
    for (int q = 0; q < 32; q++) a += h1s[q] * w_k2[q*32 + lane];
    h2s[lane] = silu(a);
  }
  __syncthreads();
  float a = b_k3[lane];
  #pragma unroll
  for (int q = 0; q < 32; q++) a += h2s[q] * w_k3[q*64 + lane];
  ws[WS_KW + tap*64 + lane] = a;
}

// ---- input proj + dwconv/silu/pointwise : 4 pixels per block ----
__global__ __launch_bounds__(256) void k_proj(
    const float* __restrict__ x,
    const float* __restrict__ w_ip, const float* __restrict__ b_ip,
    const float* __restrict__ w_dw, const float* __restrict__ b_dw,
    const float* __restrict__ w_pw, const float* __restrict__ b_pw,
    float* __restrict__ ws)
{
  int t = threadIdx.x;
  int px = t >> 6, c = t & 63;
  int pix = blockIdx.x * 4 + px;
  int b = pix >> 10, h = (pix >> 5) & 31, w = pix & 31;
  __shared__ float xs[4][64], ys[4][64];
  xs[px][c] = x[pix*64 + c];
  float acc = b_dw[c];
  #pragma unroll
  for (int dh = -1; dh <= 1; dh++) {
    int hh = h + dh;
    if (hh < 0 || hh > 31) continue;
    #pragma unroll
    for (int dw2 = -1; dw2 <= 1; dw2++) {
      int wp = w + dw2;
      if (wp < 0 || wp > 31) continue;
      acc += x[(((b*32 + hh)*32 + wp) << 6) + c] * w_dw[((dh+1)*3 + (dw2+1))*64 + c];
    }
  }
  ys[px][c] = silu(acc);
  __syncthreads();
  float p1 = b_ip[c], p2 = b_pw[c];
  #pragma unroll 8
  for (int k = 0; k < 64; k++) {
    p1 += xs[px][k] * w_ip[k*64 + c];
    p2 += ys[px][k] * w_pw[k*64 + c];
  }
  ws[WS_XPROJ + pix*64 + c] = p1;
  ws[WS_XDW   + pix*64 + c] = p2;
}

// ---- main fused: heads matvec + softmax + deform sampling, 4 px/block ----
__global__ __launch_bounds__(512, 4) void k_main(
    const float* __restrict__ raw_sigma,
    const float* __restrict__ base_scale,
    const float* __restrict__ w_off, const float* __restrict__ b_off,
    const float* __restrict__ w_msk, const float* __restrict__ b_msk,
    float* __restrict__ ws)
{
  __shared__ float xdT[256];        // [k][px]
  __shared__ float env_s[KK2];
  __shared__ float off_s[4*OFFC];   // [px][1800]
  __shared__ float msk_s[4*MSKC];   // [px][900]  (attn after softmax)
  __shared__ float red_s[16];
  __shared__ float ent_sh[16];
  __shared__ float env_sum;

  int t = threadIdx.x;              // 0..511
  int pix0 = blockIdx.x * 4;
  int b = pix0 >> 10;

  // env (+stage xdT)
  float sp = log1pf(__expf(raw_sigma[0]));
  float sigma = fminf(fmaxf(sp, 1e-3f), 0.5f);
  float envv = 0.f;
  if (t < KK2) {
    int i = t / 15, j = t % 15;
    float gi = -0.5f + (float)i * (1.0f/14.0f);
    float gj = -0.5f + (float)j * (1.0f/14.0f);
    envv = __expf(-(gi*gi + gj*gj) / (2.f*sigma*sigma));
  }
  if (t < 256) {
    int px = t >> 6, k = t & 63;
    xdT[k*4 + px] = ws[WS_XDW + (pix0 + px)*64 + k];
  }
  // block-reduce env sum (wave shfl + LDS)
  {
    float v = envv;
    #pragma unroll
    for (int m = 32; m > 0; m >>= 1) v += __shfl_xor(v, m);
    if ((t & 63) == 0) red_s[t >> 6] = v;
    __syncthreads();
    if (t == 0) {
      float s = 0.f;
      #pragma unroll
      for (int q = 0; q < 8; q++) s += red_s[q];
      env_sum = fmaxf(s, 1e-8f);
    }
    __syncthreads();
    if (t < KK2) env_s[t] = envv / env_sum;
  }

  // ---- head matvecs: 6 output cols/thread x 4 px (float4 acc, comp=px) ----
  int o0 = t, o1 = t + 512, o2 = t + 1024, o3 = t + 1536;
  int q0 = t, q1 = t + 512;
  int o3c = min(o3, OFFC - 1);
  int q1c = min(q1, MSKC - 1);
  const float* p0 = w_off + o0;
  const float* p1 = w_off + o1;
  const float* p2 = w_off + o2;
  const float* p3 = w_off + o3c;
  const float* p4 = w_msk + q0;
  const float* p5 = w_msk + q1c;
  float4 a0 = make_float4(b_off[o0], b_off[o0], b_off[o0], b_off[o0]);
  float4 a1 = make_float4(b_off[o1], b_off[o1], b_off[o1], b_off[o1]);
  float4 a2 = make_float4(b_off[o2], b_off[o2], b_off[o2], b_off[o2]);
  float4 a3 = make_float4(b_off[o3c], b_off[o3c], b_off[o3c], b_off[o3c]);
  float4 a4 = make_float4(b_msk[q0], b_msk[q0], b_msk[q0], b_msk[q0]);
  float4 a5 = make_float4(b_msk[q1c], b_msk[q1c], b_msk[q1c], b_msk[q1c]);
  const float4* xv = (const float4*)xdT;
  #pragma unroll 2
  for (int k = 0; k < 64; k++) {
    float4 xk = xv[k];
    float w0 = *p0, w1 = *p1, w2 = *p2, w3 = *p3, w4 = *p4, w5 = *p5;
    a0.x += xk.x*w0; a0.y += xk.y*w0; a0.z += xk.z*w0; a0.w += xk.w*w0;
    a1.x += xk.x*w1; a1.y += xk.y*w1; a1.z += xk.z*w1; a1.w += xk.w*w1;
    a2.x += xk.x*w2; a2.y += xk.y*w2; a2.z += xk.z*w2; a2.w += xk.w*w2;
    a3.x += xk.x*w3; a3.y += xk.y*w3; a3.z += xk.z*w3; a3.w += xk.w*w3;
    a4.x += xk.x*w4; a4.y += xk.y*w4; a4.z += xk.z*w4; a4.w += xk.w*w4;
    a5.x += xk.x*w5; a5.y += xk.y*w5; a5.z += xk.z*w5; a5.w += xk.w*w5;
    p0 += OFFC; p1 += OFFC; p2 += OFFC; p3 += OFFC; p4 += MSKC; p5 += MSKC;
  }
  float scale = base_scale[0];
  float offreg = 0.f;
  {
    float v;
    v = a0.x*scale; off_s[0*OFFC + o0] = v; offreg += v*v;
    v = a0.y*scale; off_s[1*OFFC + o0] = v; offreg += v*v;
    v = a0.z*scale; off_s[2*OFFC + o0] = v; offreg += v*v;
    v = a0.w*scale; off_s[3*OFFC + o0] = v; offreg += v*v;
    v = a1.x*scale; off_s[0*OFFC + o1] = v; offreg += v*v;
    v = a1.y*scale; off_s[1*OFFC + o1] = v; offreg += v*v;
    v = a1.z*scale; off_s[2*OFFC + o1] = v; offreg += v*v;
    v = a1.w*scale; off_s[3*OFFC + o1] = v; offreg += v*v;
    v = a2.x*scale; off_s[0*OFFC + o2] = v; offreg += v*v;
    v = a2.y*scale; off_s[1*OFFC + o2] = v; offreg += v*v;
    v = a2.z*scale; off_s[2*OFFC + o2] = v; offreg += v*v;
    v = a2.w*scale; off_s[3*OFFC + o2] = v; offreg += v*v;
    if (o3 < OFFC) {
      v = a3.x*scale; off_s[0*OFFC + o3] = v; offreg += v*v;
      v = a3.y*scale; off_s[1*OFFC + o3] = v; offreg += v*v;
      v = a3.z*scale; off_s[2*OFFC + o3] = v; offreg += v*v;
      v = a3.w*scale; off_s[3*OFFC + o3] = v; offreg += v*v;
    }
    msk_s[0*MSKC + q0] = a4.x; msk_s[1*MSKC + q0] = a4.y;
    msk_s[2*MSKC + q0] = a4.z; msk_s[3*MSKC + q0] = a4.w;
    if (q1 < MSKC) {
      msk_s[0*MSKC + q1] = a5.x; msk_s[1*MSKC + q1] = a5.y;
      msk_s[2*MSKC + q1] = a5.z; msk_s[3*MSKC + q1] = a5.w;
    }
  }
  // offreg block reduce -> ws[WS_OFFP + blk]
  {
    #pragma unroll
    for (int m = 32; m > 0; m >>= 1) offreg += __shfl_xor(offreg, m);
    __syncthreads();   // also guards off_s/msk_s stores before softmax reads
    if ((t & 63) == 0) red_s[t >> 6] = offreg;
    __syncthreads();
    if (t == 0) {
      float s = 0.f;
      #pragma unroll
      for (int q = 0; q < 8; q++) s += red_s[q];
      ws[WS_OFFP + blockIdx.x] = s;
    }
  }

  // ---- softmax: wave wv handles pairs wv, wv+8 ; pair=(px,g) ----
  int wv = t >> 6, lane = t & 63;
  #pragma unroll
  for (int rep = 0; rep < 2; rep++) {
    int pair = wv + rep*8;
    int px = pair >> 2, g = pair & 3;
    float v[4];
    float m = -INFINITY;
    #pragma unroll
    for (int kk = 0; kk < 4; kk++) {
      int p = lane + kk*64;
      if (p < KK2) { v[kk] = msk_s[px*MSKC + g*KK2 + p] * env_s[p]; m = fmaxf(m, v[kk]); }
      else v[kk] = -INFINITY;
    }
    #pragma unroll
    for (int s = 32; s > 0; s >>= 1) m = fmaxf(m, __shfl_xor(m, s));
    float sum = 0.f;
    #pragma unroll
    for (int kk = 0; kk < 4; kk++) {
      int p = lane + kk*64;
      if (p < KK2) { v[kk] = __expf(v[kk] - m); sum += v[kk]; }
    }
    #pragma unroll
    for (int s = 32; s > 0; s >>= 1) sum += __shfl_xor(sum, s);
    float inv = 1.f / sum;
    float ent = 0.f;
    #pragma unroll
    for (int kk = 0; kk < 4; kk++) {
      int p = lane + kk*64;
      if (p < KK2) {
        float a = v[kk] * inv;
        msk_s[px*MSKC + g*KK2 + p] = a;
        ent += a * __logf(a + 1e-8f);
      }
    }
    #pragma unroll
    for (int s = 32; s > 0; s >>= 1) ent += __shfl_xor(ent, s);
    if (lane == 0) ent_sh[pair] = ent;
  }
  __syncthreads();
  if (t < 4) ws[WS_ENTP + pix0 + t] =
      ent_sh[t*4] + ent_sh[t*4+1] + ent_sh[t*4+2] + ent_sh[t*4+3];

  // ---- sampling: wave = 16 tap-streams x 4 channel-quads ----
  const float* xp = ws + WS_XPROJ + (size_t)(b << 10)*64;
  int ts = lane >> 2, cl = lane & 3;
  #pragma unroll
  for (int rep = 0; rep < 2; rep++) {
    int pair = wv + rep*8;
    int px = pair >> 2, g = pair & 3;
    int pix = pix0 + px;
    int h = (pix >> 5) & 31, w = pix & 31;
    int cb = g*16 + cl*4;
    float4 acc = make_float4(0.f, 0.f, 0.f, 0.f);
    for (int p = ts; p < KK2; p += 16) {
      float at = msk_s[px*MSKC + g*KK2 + p];
      float2 o01 = *(const float2*)&off_s[px*OFFC + g*450 + p*2];
      float abs_h = (float)(h + (p/15 - 7)) + o01.x;
      float abs_w = (float)(w + (p%15 - 7)) + o01.y;
      float ah = fminf(fmaxf(abs_h, 0.f), 31.f);
      float aw = fminf(fmaxf(abs_w, 0.f), 31.f);
      int hf = (int)floorf(ah);
      int wf = (int)floorf(aw);
      int hc = min(hf + 1, 31), wc = min(wf + 1, 31);
      float hw_ = ah - (float)hf, ww_ = aw - (float)wf;
      float s = (abs_h < 0.f || abs_h > 31.f || abs_w < 0.f || abs_w > 31.f) ? 0.f : at;
      float w00 = (1.f-hw_)*(1.f-ww_)*s, w01 = (1.f-hw_)*ww_*s;
      float w10 = hw_*(1.f-ww_)*s,       w11 = hw_*ww_*s;
      const float4 vff = *(const float4*)&xp[((hf*32 + wf) << 6) + cb];
      const float4 vfc = *(const float4*)&xp[((hf*32 + wc) << 6) + cb];
      const float4 vcf = *(const float4*)&xp[((hc*32 + wf) << 6) + cb];
      const float4 vcc = *(const float4*)&xp[((hc*32 + wc) << 6) + cb];
      const float4 kwv = *(const float4*)&ws[WS_KW + g*3600 + p*16 + cl*4];
      acc.x += (vff.x*w00 + vfc.x*w01 + vcf.x*w10 + vcc.x*w11) * kwv.x;
      acc.y += (vff.y*w00 + vfc.y*w01 + vcf.y*w10 + vcc.y*w11) * kwv.y;
      acc.z += (vff.z*w00 + vfc.z*w01 + vcf.z*w10 + vcc.z*w11) * kwv.z;
      acc.w += (vff.w*w00 + vfc.w*w01 + vcf.w*w10 + vcc.w*w11) * kwv.w;
    }
    #pragma unroll
    for (int m = 4; m < 64; m <<= 1) {
      acc.x += __shfl_xor(acc.x, m);
      acc.y += __shfl_xor(acc.y, m);
      acc.z += __shfl_xor(acc.z, m);
      acc.w += __shfl_xor(acc.w, m);
    }
    if (lane < 4) *(float4*)&ws[WS_OUT + pix*64 + cb] = acc;
  }
}

__global__ __launch_bounds__(256) void k_reduce(float* __restrict__ ws, float* __restrict__ d_out)
{
  __shared__ float red[256];
  int t = threadIdx.x, blk = blockIdx.x;
  if (blk < 2) {
    int b = blk;
    int c = t & 63, str = t >> 6;
    float s = 0.f;
    for (int p = str; p < 1024; p += 4) s += ws[WS_OUT + ((b*1024 + p) << 6) + c];
    red[t] = s;
    __syncthreads();
    if (t < 64) ws[WS_POOL + b*64 + t] =
      (red[t] + red[t+64] + red[t+128] + red[t+192]) * (1.f/1024.f);
  } else if (blk == 2) {
    float s = 0.f;
    for (int i = t; i < NPIX; i += 256) s += ws[WS_ENTP + i];
    red[t] = s; __syncthreads();
    for (int sf = 128; sf > 0; sf >>= 1) { if (t < sf) red[t] += red[t+sf]; __syncthreads(); }
    if (t == 0) d_out[NPIX*64 + 1] = red[0] * (1.f/8192.f);     // -entropy
  } else {
    float s = 0.f;
    for (int i = t; i < 512; i += 256) s += ws[WS_OFFP + i];
    red[t] = s; __syncthreads();
    for (int sf = 128; sf > 0; sf >>= 1) { if (t < sf) red[t] += red[t+sf]; __syncthreads(); }
    if (t == 0) d_out[NPIX*64] = red[0] * (1.f/3686400.f);      // offset_reg
  }
}

__global__ __launch_bounds__(128) void k_se(
    const float* __restrict__ w_fc1, const float* __restrict__ b_fc1,
    const float* __restrict__ w_fc2, const float* __restrict__ b_fc2,
    float* __restrict__ ws)
{
  __shared__ float hsh[2][16];
  int t = threadIdx.x;
  if (t < 32) {
    int b = t >> 4, r = t & 15;
    float a = b_fc1[r];
    for (int c = 0; c < 64; c++) a += ws[WS_POOL + b*64 + c] * w_fc1[c*16 + r];
    hsh[b][r] = silu(a);
  }
  __syncthreads();
  int b = t >> 6, c = t & 63;
  float a = b_fc2[c];
  #pragma unroll
  for (int r = 0; r < 16; r++) a += hsh[b][r] * w_fc2[r*64 + c];
  ws[WS_GATE + b*64 + c] = 1.f / (1.f + __expf(-a));
}

__global__ __launch_bounds__(256) void k_final(
    const float* __restrict__ w_op, const float* __restrict__ b_op,
    const float* __restrict__ ws, float* __restrict__ d_out)
{
  int t = threadIdx.x;
  int px = t >> 6, c = t & 63;
  int pix = blockIdx.x * 4 + px;
  int b = pix >> 10;
  __shared__ float sc[4][64];
  sc[px][c] = ws[WS_OUT + pix*64 + c] * ws[WS_GATE + b*64 + c];
  __syncthreads();
  float a = b_op[c];
  #pragma unroll 8
  for (int k = 0; k < 64; k++) a += sc[px][k] * w_op[k*64 + c];
  d_out[pix*64 + c] = a;
}

extern "C" void kernel_launch(void* const* d_in, const int* in_sizes, int n_in,
                              void* d_out, int out_size, void* d_ws, size_t ws_size,
                              hipStream_t stream)
{
  const float* x     = (const float*)d_in[0];
  const float* rsig  = (const float*)d_in[1];
  const float* bos   = (const float*)d_in[2];
  const float* w_ip  = (const float*)d_in[3];
  const float* b_ip  = (const float*)d_in[4];
  const float* w_op  = (const float*)d_in[5];
  const float* b_op  = (const float*)d_in[6];
  const float* w_dw  = (const float*)d_in[7];
  const float* b_dw  = (const float*)d_in[8];
  const float* w_pw  = (const float*)d_in[9];
  const float* b_pw  = (const float*)d_in[10];
  const float* w_off = (const float*)d_in[11];
  const float* b_off = (const float*)d_in[12];
  const float* w_msk = (const float*)d_in[13];
  const float* b_msk = (const float*)d_in[14];
  const float* w_k1  = (const float*)d_in[15];
  const float* b_k1  = (const float*)d_in[16];
  const float* w_k2  = (const float*)d_in[17];
  const float* b_k2  = (const float*)d_in[18];
  const float* w_k3  = (const float*)d_in[19];
  const float* b_k3  = (const float*)d_in[20];
  const float* w_fc1 = (const float*)d_in[21];
  const float* b_fc1 = (const float*)d_in[22];
  const float* w_fc2 = (const float*)d_in[23];
  const float* b_fc2 = (const float*)d_in[24];
  float* ws  = (float*)d_ws;
  float* out = (float*)d_out;

  hipLaunchKernelGGL(k_kmlp, dim3(KK2), dim3(64), 0, stream,
                     w_k1, b_k1, w_k2, b_k2, w_k3, b_k3, ws);
  hipLaunchKernelGGL(k_proj, dim3(512), dim3(256), 0, stream,
                     x, w_ip, b_ip, w_dw, b_dw, w_pw, b_pw, ws);
  hipLaunchKernelGGL(k_main, dim3(512), dim3(512), 0, stream,
                     rsig, bos, w_off, b_off, w_msk, b_msk, ws);
  hipLaunchKernelGGL(k_reduce, dim3(4), dim3(256), 0, stream, ws, out);
  hipLaunchKernelGGL(k_se, dim3(1), dim3(128), 0, stream,
                     w_fc1, b_fc1, w_fc2, b_fc2, ws);
  hipLaunchKernelGGL(k_final, dim3(512), dim3(256), 0, stream,
                     w_op, b_op, ws, out);
}

// Round 3
// 54.042 us; speedup vs baseline: 3.6079x; 2.1664x over previous
//
#include <hip/hip_runtime.h>
#include <math.h>

#define KK2 225
#define NPIX 2048
#define OFFC 1800
#define MSKC 900

// ws layout (float offsets)
#define WS_KW    0                       // 14400 (kernel MLP out, [225][64] row-major)
#define WS_XPROJ 16384                   // 131072
#define WS_XDW   (16384+131072)          // 131072
#define WS_OUT   (16384+2*131072)        // 131072
#define WS_POOL  (16384+3*131072)        // 128
#define WS_GATE  (WS_POOL+128)           // 128
#define WS_ENTP  (WS_GATE+128)           // 2048 (per-pixel entropy partial)
#define WS_OFFP  (WS_ENTP+2048)          // 512  (per-k_main-block offreg partial)
#define WS_PART2 (WS_OFFP+512)           // 4096 ([64 chunks][64 ch] pooled partials)

__device__ __forceinline__ float silu(float a) { return a / (1.f + __expf(-a)); }

// ---- fused: input proj + dwconv (blocks 0..511) ; kernel MLP (blocks 512..568) ----
__global__ __launch_bounds__(256) void k_pre(
    const float* __restrict__ x,
    const float* __restrict__ w_ip, const float* __restrict__ b_ip,
    const float* __restrict__ w_dw, const float* __restrict__ b_dw,
    const float* __restrict__ w_pw, const float* __restrict__ b_pw,
    const float* __restrict__ w_k1, const float* __restrict__ b_k1,
    const float* __restrict__ w_k2, const float* __restrict__ b_k2,
    const float* __restrict__ w_k3, const float* __restrict__ b_k3,
    float* __restrict__ ws)
{
  int t = threadIdx.x;
  if (blockIdx.x < 512) {
    int px = t >> 6, c = t & 63;
    int pix = blockIdx.x * 4 + px;
    int b = pix >> 10, h = (pix >> 5) & 31, w = pix & 31;
    __shared__ float xs[4][64], ys[4][64];
    xs[px][c] = x[pix*64 + c];
    float acc = b_dw[c];
    #pragma unroll
    for (int dh = -1; dh <= 1; dh++) {
      int hh = h + dh;
      if (hh < 0 || hh > 31) continue;
      #pragma unroll
      for (int dw2 = -1; dw2 <= 1; dw2++) {
        int wp = w + dw2;
        if (wp < 0 || wp > 31) continue;
        acc += x[(((b*32 + hh)*32 + wp) << 6) + c] * w_dw[((dh+1)*3 + (dw2+1))*64 + c];
      }
    }
    ys[px][c] = silu(acc);
    __syncthreads();
    float p1 = b_ip[c], p2 = b_pw[c];
    #pragma unroll 8
    for (int k = 0; k < 64; k++) {
      p1 += xs[px][k] * w_ip[k*64 + c];
      p2 += ys[px][k] * w_pw[k*64 + c];
    }
    ws[WS_XPROJ + pix*64 + c] = p1;
    ws[WS_XDW   + pix*64 + c] = p2;
  } else {
    // kernel MLP: 4 taps per block, 64 lanes per tap
    __shared__ float h1s[4][32], h2s[4][32];
    int tl = t >> 6, lane = t & 63;
    int tap = (blockIdx.x - 512) * 4 + tl;
    int tapc = min(tap, KK2 - 1);
    int i = tapc / 15, j = tapc % 15;
    float gi = -0.5f + (float)i * (1.0f/14.0f);
    float gj = -0.5f + (float)j * (1.0f/14.0f);
    float p0 = gi * 2.f, p1 = gj * 2.f;
    if (lane < 32) {
      float a = p0 * w_k1[lane] + p1 * w_k1[32 + lane] + b_k1[lane];
      h1s[tl][lane] = silu(a);
    }
    __syncthreads();
    if (lane < 32) {
      float a = b_k2[lane];
      #pragma unroll
      for (int q = 0; q < 32; q++) a += h1s[tl][q] * w_k2[q*32 + lane];
      h2s[tl][lane] = silu(a);
    }
    __syncthreads();
    float a = b_k3[lane];
    #pragma unroll
    for (int q = 0; q < 32; q++) a += h2s[tl][q] * w_k3[q*64 + lane];
    if (tap < KK2) ws[WS_KW + tap*64 + lane] = a;
  }
}

// ---- main fused: heads matvec + softmax + deform sampling, 4 px/block ----
__global__ __launch_bounds__(512, 4) void k_main(
    const float* __restrict__ raw_sigma,
    const float* __restrict__ base_scale,
    const float* __restrict__ w_off, const float* __restrict__ b_off,
    const float* __restrict__ w_msk, const float* __restrict__ b_msk,
    float* __restrict__ ws)
{
  __shared__ float xdT[256];        // [k][px]
  __shared__ float env_s[KK2];
  __shared__ float off_s[4*OFFC];   // [px][1800]
  __shared__ float msk_s[4*MSKC];   // [px][900]  (attn after softmax)
  __shared__ float red_s[16];
  __shared__ float ent_sh[16];
  __shared__ float env_sum;

  int t = threadIdx.x;              // 0..511
  int pix0 = blockIdx.x * 4;
  int b = pix0 >> 10;

  // env (+stage xdT)
  float sp = log1pf(__expf(raw_sigma[0]));
  float sigma = fminf(fmaxf(sp, 1e-3f), 0.5f);
  float envv = 0.f;
  if (t < KK2) {
    int i = t / 15, j = t % 15;
    float gi = -0.5f + (float)i * (1.0f/14.0f);
    float gj = -0.5f + (float)j * (1.0f/14.0f);
    envv = __expf(-(gi*gi + gj*gj) / (2.f*sigma*sigma));
  }
  if (t < 256) {
    int px = t >> 6, k = t & 63;
    xdT[k*4 + px] = ws[WS_XDW + (pix0 + px)*64 + k];
  }
  {
    float v = envv;
    #pragma unroll
    for (int m = 32; m > 0; m >>= 1) v += __shfl_xor(v, m);
    if ((t & 63) == 0) red_s[t >> 6] = v;
    __syncthreads();
    if (t == 0) {
      float s = 0.f;
      #pragma unroll
      for (int q = 0; q < 8; q++) s += red_s[q];
      env_sum = fmaxf(s, 1e-8f);
    }
    __syncthreads();
    if (t < KK2) env_s[t] = envv / env_sum;
  }

  // ---- head matvecs: 6 output cols/thread x 4 px (float4 acc, comp=px) ----
  int o0 = t, o1 = t + 512, o2 = t + 1024, o3 = t + 1536;
  int q0 = t, q1 = t + 512;
  int o3c = min(o3, OFFC - 1);
  int q1c = min(q1, MSKC - 1);
  const float* p0 = w_off + o0;
  const float* p1 = w_off + o1;
  const float* p2 = w_off + o2;
  const float* p3 = w_off + o3c;
  const float* p4 = w_msk + q0;
  const float* p5 = w_msk + q1c;
  float4 a0 = make_float4(b_off[o0], b_off[o0], b_off[o0], b_off[o0]);
  float4 a1 = make_float4(b_off[o1], b_off[o1], b_off[o1], b_off[o1]);
  float4 a2 = make_float4(b_off[o2], b_off[o2], b_off[o2], b_off[o2]);
  float4 a3 = make_float4(b_off[o3c], b_off[o3c], b_off[o3c], b_off[o3c]);
  float4 a4 = make_float4(b_msk[q0], b_msk[q0], b_msk[q0], b_msk[q0]);
  float4 a5 = make_float4(b_msk[q1c], b_msk[q1c], b_msk[q1c], b_msk[q1c]);
  const float4* xv = (const float4*)xdT;
  #pragma unroll 2
  for (int k = 0; k < 64; k++) {
    float4 xk = xv[k];
    float w0 = *p0, w1 = *p1, w2 = *p2, w3 = *p3, w4 = *p4, w5 = *p5;
    a0.x += xk.x*w0; a0.y += xk.y*w0; a0.z += xk.z*w0; a0.w += xk.w*w0;
    a1.x += xk.x*w1; a1.y += xk.y*w1; a1.z += xk.z*w1; a1.w += xk.w*w1;
    a2.x += xk.x*w2; a2.y += xk.y*w2; a2.z += xk.z*w2; a2.w += xk.w*w2;
    a3.x += xk.x*w3; a3.y += xk.y*w3; a3.z += xk.z*w3; a3.w += xk.w*w3;
    a4.x += xk.x*w4; a4.y += xk.y*w4; a4.z += xk.z*w4; a4.w += xk.w*w4;
    a5.x += xk.x*w5; a5.y += xk.y*w5; a5.z += xk.z*w5; a5.w += xk.w*w5;
    p0 += OFFC; p1 += OFFC; p2 += OFFC; p3 += OFFC; p4 += MSKC; p5 += MSKC;
  }
  float scale = base_scale[0];
  float offreg = 0.f;
  {
    float v;
    v = a0.x*scale; off_s[0*OFFC + o0] = v; offreg += v*v;
    v = a0.y*scale; off_s[1*OFFC + o0] = v; offreg += v*v;
    v = a0.z*scale; off_s[2*OFFC + o0] = v; offreg += v*v;
    v = a0.w*scale; off_s[3*OFFC + o0] = v; offreg += v*v;
    v = a1.x*scale; off_s[0*OFFC + o1] = v; offreg += v*v;
    v = a1.y*scale; off_s[1*OFFC + o1] = v; offreg += v*v;
    v = a1.z*scale; off_s[2*OFFC + o1] = v; offreg += v*v;
    v = a1.w*scale; off_s[3*OFFC + o1] = v; offreg += v*v;
    v = a2.x*scale; off_s[0*OFFC + o2] = v; offreg += v*v;
    v = a2.y*scale; off_s[1*OFFC + o2] = v; offreg += v*v;
    v = a2.z*scale; off_s[2*OFFC + o2] = v; offreg += v*v;
    v = a2.w*scale; off_s[3*OFFC + o2] = v; offreg += v*v;
    if (o3 < OFFC) {
      v = a3.x*scale; off_s[0*OFFC + o3] = v; offreg += v*v;
      v = a3.y*scale; off_s[1*OFFC + o3] = v; offreg += v*v;
      v = a3.z*scale; off_s[2*OFFC + o3] = v; offreg += v*v;
      v = a3.w*scale; off_s[3*OFFC + o3] = v; offreg += v*v;
    }
    msk_s[0*MSKC + q0] = a4.x; msk_s[1*MSKC + q0] = a4.y;
    msk_s[2*MSKC + q0] = a4.z; msk_s[3*MSKC + q0] = a4.w;
    if (q1 < MSKC) {
      msk_s[0*MSKC + q1] = a5.x; msk_s[1*MSKC + q1] = a5.y;
      msk_s[2*MSKC + q1] = a5.z; msk_s[3*MSKC + q1] = a5.w;
    }
  }
  {
    #pragma unroll
    for (int m = 32; m > 0; m >>= 1) offreg += __shfl_xor(offreg, m);
    __syncthreads();   // also guards off_s/msk_s stores before softmax reads
    if ((t & 63) == 0) red_s[t >> 6] = offreg;
    __syncthreads();
    if (t == 0) {
      float s = 0.f;
      #pragma unroll
      for (int q = 0; q < 8; q++) s += red_s[q];
      ws[WS_OFFP + blockIdx.x] = s;
    }
  }

  // ---- softmax: wave wv handles pairs wv, wv+8 ; pair=(px,g) ----
  int wv = t >> 6, lane = t & 63;
  #pragma unroll
  for (int rep = 0; rep < 2; rep++) {
    int pair = wv + rep*8;
    int px = pair >> 2, g = pair & 3;
    float v[4];
    float m = -INFINITY;
    #pragma unroll
    for (int kk = 0; kk < 4; kk++) {
      int p = lane + kk*64;
      if (p < KK2) { v[kk] = msk_s[px*MSKC + g*KK2 + p] * env_s[p]; m = fmaxf(m, v[kk]); }
      else v[kk] = -INFINITY;
    }
    #pragma unroll
    for (int s = 32; s > 0; s >>= 1) m = fmaxf(m, __shfl_xor(m, s));
    float sum = 0.f;
    #pragma unroll
    for (int kk = 0; kk < 4; kk++) {
      int p = lane + kk*64;
      if (p < KK2) { v[kk] = __expf(v[kk] - m); sum += v[kk]; }
    }
    #pragma unroll
    for (int s = 32; s > 0; s >>= 1) sum += __shfl_xor(sum, s);
    float inv = 1.f / sum;
    float ent = 0.f;
    #pragma unroll
    for (int kk = 0; kk < 4; kk++) {
      int p = lane + kk*64;
      if (p < KK2) {
        float a = v[kk] * inv;
        msk_s[px*MSKC + g*KK2 + p] = a;
        ent += a * __logf(a + 1e-8f);
      }
    }
    #pragma unroll
    for (int s = 32; s > 0; s >>= 1) ent += __shfl_xor(ent, s);
    if (lane == 0) ent_sh[pair] = ent;
  }
  __syncthreads();
  if (t < 4) ws[WS_ENTP + pix0 + t] =
      ent_sh[t*4] + ent_sh[t*4+1] + ent_sh[t*4+2] + ent_sh[t*4+3];

  // ---- sampling: wave = 16 tap-streams x 4 channel-quads ----
  const float* xp = ws + WS_XPROJ + (size_t)(b << 10)*64;
  int ts = lane >> 2, cl = lane & 3;
  #pragma unroll
  for (int rep = 0; rep < 2; rep++) {
    int pair = wv + rep*8;
    int px = pair >> 2, g = pair & 3;
    int pix = pix0 + px;
    int h = (pix >> 5) & 31, w = pix & 31;
    int cb = g*16 + cl*4;
    float4 acc = make_float4(0.f, 0.f, 0.f, 0.f);
    for (int p = ts; p < KK2; p += 16) {
      float at = msk_s[px*MSKC + g*KK2 + p];
      float2 o01 = *(const float2*)&off_s[px*OFFC + g*450 + p*2];
      float abs_h = (float)(h + (p/15 - 7)) + o01.x;
      float abs_w = (float)(w + (p%15 - 7)) + o01.y;
      float ah = fminf(fmaxf(abs_h, 0.f), 31.f);
      float aw = fminf(fmaxf(abs_w, 0.f), 31.f);
      int hf = (int)floorf(ah);
      int wf = (int)floorf(aw);
      int hc = min(hf + 1, 31), wc = min(wf + 1, 31);
      float hw_ = ah - (float)hf, ww_ = aw - (float)wf;
      float s = (abs_h < 0.f || abs_h > 31.f || abs_w < 0.f || abs_w > 31.f) ? 0.f : at;
      float w00 = (1.f-hw_)*(1.f-ww_)*s, w01 = (1.f-hw_)*ww_*s;
      float w10 = hw_*(1.f-ww_)*s,       w11 = hw_*ww_*s;
      const float4 vff = *(const float4*)&xp[((hf*32 + wf) << 6) + cb];
      const float4 vfc = *(const float4*)&xp[((hf*32 + wc) << 6) + cb];
      const float4 vcf = *(const float4*)&xp[((hc*32 + wf) << 6) + cb];
      const float4 vcc = *(const float4*)&xp[((hc*32 + wc) << 6) + cb];
      const float4 kwv = *(const float4*)&ws[WS_KW + g*3600 + p*16 + cl*4];
      acc.x += (vff.x*w00 + vfc.x*w01 + vcf.x*w10 + vcc.x*w11) * kwv.x;
      acc.y += (vff.y*w00 + vfc.y*w01 + vcf.y*w10 + vcc.y*w11) * kwv.y;
      acc.z += (vff.z*w00 + vfc.z*w01 + vcf.z*w10 + vcc.z*w11) * kwv.z;
      acc.w += (vff.w*w00 + vfc.w*w01 + vcf.w*w10 + vcc.w*w11) * kwv.w;
    }
    #pragma unroll
    for (int m = 4; m < 64; m <<= 1) {
      acc.x += __shfl_xor(acc.x, m);
      acc.y += __shfl_xor(acc.y, m);
      acc.z += __shfl_xor(acc.z, m);
      acc.w += __shfl_xor(acc.w, m);
    }
    if (lane < 4) *(float4*)&ws[WS_OUT + pix*64 + cb] = acc;
  }
}

// ---- parallel reductions: 64 pooled-chunk blocks + entropy + offreg ----
__global__ __launch_bounds__(256) void k_red(float* __restrict__ ws, float* __restrict__ d_out)
{
  __shared__ float red[256];
  int t = threadIdx.x, blk = blockIdx.x;
  if (blk < 64) {
    int b = blk >> 5, chunk = blk & 31;
    int c = t & 63, str = t >> 6;
    const float* base = ws + WS_OUT + (size_t)((b*1024 + chunk*32) << 6) + c;
    float s = 0.f;
    #pragma unroll
    for (int i = 0; i < 8; i++) s += base[((str + i*4) << 6)];
    red[t] = s;
    __syncthreads();
    if (t < 64) ws[WS_PART2 + blk*64 + t] =
      red[t] + red[t+64] + red[t+128] + red[t+192];
  } else if (blk == 64) {
    float s = 0.f;
    #pragma unroll
    for (int i = 0; i < 8; i++) s += ws[WS_ENTP + t + i*256];
    #pragma unroll
    for (int m = 32; m > 0; m >>= 1) s += __shfl_xor(s, m);
    if ((t & 63) == 0) red[t >> 6] = s;
    __syncthreads();
    if (t == 0) d_out[NPIX*64 + 1] = (red[0] + red[1] + red[2] + red[3]) * (1.f/8192.f);
  } else {
    float s = 0.f;
    #pragma unroll
    for (int i = 0; i < 2; i++) s += ws[WS_OFFP + t + i*256];
    #pragma unroll
    for (int m = 32; m > 0; m >>= 1) s += __shfl_xor(s, m);
    if ((t & 63) == 0) red[t >> 6] = s;
    __syncthreads();
    if (t == 0) d_out[NPIX*64] = (red[0] + red[1] + red[2] + red[3]) * (1.f/3686400.f);
  }
}

// ---- SE gate (includes stage-2 pooled sum) ----
__global__ __launch_bounds__(128) void k_se(
    const float* __restrict__ w_fc1, const float* __restrict__ b_fc1,
    const float* __restrict__ w_fc2, const float* __restrict__ b_fc2,
    float* __restrict__ ws)
{
  __shared__ float pool_s[2][64];
  __shared__ float hsh[2][16];
  int t = threadIdx.x;
  int b = t >> 6, c = t & 63;
  {
    float s = 0.f;
    #pragma unroll
    for (int ch = 0; ch < 32; ch++) s += ws[WS_PART2 + (b*32 + ch)*64 + c];
    pool_s[b][c] = s * (1.f/1024.f);
  }
  __syncthreads();
  if (t < 32) {
    int bb = t >> 4, r = t & 15;
    float a = b_fc1[r];
    #pragma unroll 16
    for (int cc = 0; cc < 64; cc++) a += pool_s[bb][cc] * w_fc1[cc*16 + r];
    hsh[bb][r] = silu(a);
  }
  __syncthreads();
  float a = b_fc2[c];
  #pragma unroll
  for (int r = 0; r < 16; r++) a += hsh[b][r] * w_fc2[r*64 + c];
  ws[WS_GATE + b*64 + c] = 1.f / (1.f + __expf(-a));
}

__global__ __launch_bounds__(256) void k_final(
    const float* __restrict__ w_op, const float* __restrict__ b_op,
    const float* __restrict__ ws, float* __restrict__ d_out)
{
  int t = threadIdx.x;
  int px = t >> 6, c = t & 63;
  int pix = blockIdx.x * 4 + px;
  int b = pix >> 10;
  __shared__ float sc[4][64];
  sc[px][c] = ws[WS_OUT + pix*64 + c] * ws[WS_GATE + b*64 + c];
  __syncthreads();
  float a = b_op[c];
  #pragma unroll 8
  for (int k = 0; k < 64; k++) a += sc[px][k] * w_op[k*64 + c];
  d_out[pix*64 + c] = a;
}

extern "C" void kernel_launch(void* const* d_in, const int* in_sizes, int n_in,
                              void* d_out, int out_size, void* d_ws, size_t ws_size,
                              hipStream_t stream)
{
  const float* x     = (const float*)d_in[0];
  const float* rsig  = (const float*)d_in[1];
  const float* bos   = (const float*)d_in[2];
  const float* w_ip  = (const float*)d_in[3];
  const float* b_ip  = (const float*)d_in[4];
  const float* w_op  = (const float*)d_in[5];
  const float* b_op  = (const float*)d_in[6];
  const float* w_dw  = (const float*)d_in[7];
  const float* b_dw  = (const float*)d_in[8];
  const float* w_pw  = (const float*)d_in[9];
  const float* b_pw  = (const float*)d_in[10];
  const float* w_off = (const float*)d_in[11];
  const float* b_off = (const float*)d_in[12];
  const float* w_msk = (const float*)d_in[13];
  const float* b_msk = (const float*)d_in[14];
  const float* w_k1  = (const float*)d_in[15];
  const float* b_k1  = (const float*)d_in[16];
  const float* w_k2  = (const float*)d_in[17];
  const float* b_k2  = (const float*)d_in[18];
  const float* w_k3  = (const float*)d_in[19];
  const float* b_k3  = (const float*)d_in[20];
  const float* w_fc1 = (const float*)d_in[21];
  const float* b_fc1 = (const float*)d_in[22];
  const float* w_fc2 = (const float*)d_in[23];
  const float* b_fc2 = (const float*)d_in[24];
  float* ws  = (float*)d_ws;
  float* out = (float*)d_out;

  hipLaunchKernelGGL(k_pre, dim3(569), dim3(256), 0, stream,
                     x, w_ip, b_ip, w_dw, b_dw, w_pw, b_pw,
                     w_k1, b_k1, w_k2, b_k2, w_k3, b_k3, ws);
  hipLaunchKernelGGL(k_main, dim3(512), dim3(512), 0, stream,
                     rsig, bos, w_off, b_off, w_msk, b_msk, ws);
  hipLaunchKernelGGL(k_red, dim3(66), dim3(256), 0, stream, ws, out);
  hipLaunchKernelGGL(k_se, dim3(1), dim3(128), 0, stream,
                     w_fc1, b_fc1, w_fc2, b_fc2, ws);
  hipLaunchKernelGGL(k_final, dim3(512), dim3(256), 0, stream,
                     w_op, b_op, ws, out);
}